// Round 2
// baseline (1368.596 us; speedup 1.0000x reference)
//
#include <hip/hip_runtime.h>
#include <stdint.h>

#define F 64
#define RDIM 8
#define HDIM 64
#define NPATH 5

// ---------------- Kernel A: s = nfs@Wu_s ; v = nfv@Wu_v (per component) ---------
__global__ __launch_bounds__(256) void k_pre(
    const float* __restrict__ nfs, const float* __restrict__ nfv,
    const float* __restrict__ Wus, const float* __restrict__ Wuv,
    float* __restrict__ s_lin, float* __restrict__ v_lin, int N)
{
    __shared__ float4 stage[4][F];
    const int wave = threadIdx.x >> 6, lane = threadIdx.x & 63;
    const int n = blockIdx.x * 4 + wave;
    const bool act = n < N;
    if (act) {
        float xs = nfs[(size_t)n * F + lane];
        const float* pv = nfv + ((size_t)n * F + lane) * 3;
        stage[wave][lane] = make_float4(xs, pv[0], pv[1], pv[2]);
    }
    __syncthreads();
    if (!act) return;
    float as = 0.f, a0 = 0.f, a1 = 0.f, a2 = 0.f;
#pragma unroll 8
    for (int f = 0; f < F; ++f) {
        float4 x = stage[wave][f];
        float ws = Wus[f * F + lane];
        float wv = Wuv[f * F + lane];
        as += x.x * ws; a0 += x.y * wv; a1 += x.z * wv; a2 += x.w * wv;
    }
    s_lin[(size_t)n * F + lane] = as;
    float* vb = v_lin + (size_t)n * 3 * F;     // layout [n][c][f]
    vb[0 * F + lane] = a0; vb[1 * F + lane] = a1; vb[2 * F + lane] = a2;
}

// ---------------- Kernel B: radial MLP + tensor product + atomic scatter --------
__global__ __launch_bounds__(256) void k_edge(
    const float* __restrict__ vecs, const float* __restrict__ re,
    const float* __restrict__ Wr1, const float* __restrict__ Wr2,
    const int* __restrict__ senders, const int* __restrict__ receivers,
    const float* __restrict__ s_lin, const float* __restrict__ v_lin,
    float* __restrict__ agg_s, float* __restrict__ agg_v, int E)
{
    __shared__ float w2[HDIM * NPATH * F];   // 80 KB fp32 weights
    const int tid = threadIdx.x;
    for (int i = tid; i < HDIM * NPATH * F / 4; i += 256)
        ((float4*)w2)[i] = ((const float4*)Wr2)[i];
    __syncthreads();

    const int wave = tid >> 6, lane = tid & 63;
    float w1r[RDIM];
#pragma unroll
    for (int r = 0; r < RDIM; ++r) w1r[r] = Wr1[r * HDIM + lane];

    const int gwave = blockIdx.x * 4 + wave;
    const int nwaves = gridDim.x * 4;
    const int nquad = (E + 7) >> 3;

    for (int q = gwave; q < nquad; q += nwaves) {
        const int ebase = q * 8;
        // --- phase 1: h[e, lane] for 8 edges (lane = hidden unit) ---
        float hh[8];
#pragma unroll
        for (int t = 0; t < 8; ++t) {
            const int e = ebase + t;
            float h = 0.f;
            if (e < E) {
                const float* rp = re + (size_t)e * RDIM;
#pragma unroll
                for (int r = 0; r < RDIM; ++r) h += rp[r] * w1r[r];
                h = h / (1.f + __expf(-h));        // silu
            }
            hh[t] = h;
        }

        // --- phase 2: w[e,p,f] = sum_k h[e,k] * W_r2[k, p*F+f]; f = lane ---
        // h broadcast via shuffle (no LDS exchange -> no ordering hazards)
        float acc[NPATH][8];
#pragma unroll
        for (int p = 0; p < NPATH; ++p)
#pragma unroll
            for (int t = 0; t < 8; ++t) acc[p][t] = 0.f;
#pragma unroll 2
        for (int k = 0; k < HDIM; ++k) {
            float hk[8];
#pragma unroll
            for (int t = 0; t < 8; ++t) hk[t] = __shfl(hh[t], k, 64);
#pragma unroll
            for (int p = 0; p < NPATH; ++p) {
                float wv = w2[k * (NPATH * F) + p * F + lane];
#pragma unroll
                for (int t = 0; t < 8; ++t) acc[p][t] += wv * hk[t];
            }
        }

        // --- phase 3: tensor product + atomic scatter, per edge ---
#pragma unroll
        for (int t = 0; t < 8; ++t) {
            const int e = ebase + t;
            if (e >= E) continue;
            const int snd = senders[e], rcv = receivers[e];
            const float* vp = vecs + (size_t)e * 3;
            float vx = vp[0], vy = vp[1], vz = vp[2];
            float nrm = sqrtf(vx * vx + vy * vy + vz * vz);
            float inv = 1.f / (nrm + 1e-9f);
            float Yx = vx * inv, Yy = vy * inv, Yz = vz * inv;
            const float* sb = s_lin + (size_t)snd * F;
            const float* vb = v_lin + (size_t)snd * 3 * F;
            float xs = sb[lane];
            float x0 = vb[lane], x1 = vb[F + lane], x2 = vb[2 * F + lane];
            float w0 = acc[0][t], w1p = acc[1][t], w2p = acc[2][t],
                  w3p = acc[3][t], w4p = acc[4][t];
            float dvY = x0 * Yx + x1 * Yy + x2 * Yz;
            float ms = w0 * xs + w3p * dvY;
            float cr0 = x1 * Yz - x2 * Yy;
            float cr1 = x2 * Yx - x0 * Yz;
            float cr2 = x0 * Yy - x1 * Yx;
            float m0 = w1p * xs * Yx + w2p * x0 + w4p * cr0;
            float m1 = w1p * xs * Yy + w2p * x1 + w4p * cr1;
            float m2 = w1p * xs * Yz + w2p * x2 + w4p * cr2;
            float* asb = agg_s + (size_t)rcv * F;
            float* avb = agg_v + (size_t)rcv * 3 * F;
            unsafeAtomicAdd(&asb[lane], ms);
            unsafeAtomicAdd(&avb[lane], m0);
            unsafeAtomicAdd(&avb[F + lane], m1);
            unsafeAtomicAdd(&avb[2 * F + lane], m2);
        }
    }
}

// ---------------- Kernel C: linear-down, sym contraction, skip, readout ---------
__global__ __launch_bounds__(256) void k_post(
    const float* __restrict__ agg_s, const float* __restrict__ agg_v,
    const float* __restrict__ nfs, const float* __restrict__ nfv,
    const float* __restrict__ Wds, const float* __restrict__ Wdv,
    const float* __restrict__ wss, const float* __restrict__ wsv,
    const float* __restrict__ WLs, const float* __restrict__ WLv,
    const float* __restrict__ Wsks, const float* __restrict__ Wskv,
    const float* __restrict__ Wout, const int* __restrict__ specie,
    float* __restrict__ out0, float* __restrict__ out_fs,
    float* __restrict__ out_fv, int N)
{
    __shared__ float4 stA[4][F];
    __shared__ float4 stX[4][F];
    const int wave = threadIdx.x >> 6, lane = threadIdx.x & 63;
    const int n = blockIdx.x * 4 + wave;
    const bool act = n < N;
    const int sp = act ? specie[n] : 0;
    if (act) {
        float as = agg_s[(size_t)n * F + lane];
        const float* avb = agg_v + (size_t)n * 3 * F;
        stA[wave][lane] = make_float4(as, avb[lane], avb[F + lane], avb[2 * F + lane]);
        float xs = nfs[(size_t)n * F + lane];
        const float* xp = nfv + ((size_t)n * F + lane) * 3;
        stX[wave][lane] = make_float4(xs, xp[0], xp[1], xp[2]);
    }
    __syncthreads();

    float s2 = 0, v20 = 0, v21 = 0, v22 = 0, scs = 0, sc0 = 0, sc1 = 0, sc2 = 0;
    const float* Wks = Wsks + (size_t)sp * F * F;
    const float* Wkv = Wskv + (size_t)sp * F * F;
    if (act) {
#pragma unroll 4
        for (int f = 0; f < F; ++f) {
            float4 A = stA[wave][f];
            float4 X = stX[wave][f];
            float wd_s = Wds[f * F + lane], wd_v = Wdv[f * F + lane];
            s2 += A.x * wd_s; v20 += A.y * wd_v; v21 += A.z * wd_v; v22 += A.w * wd_v;
            float wk_s = Wks[f * F + lane], wk_v = Wkv[f * F + lane];
            scs += X.x * wk_s; sc0 += X.y * wk_v; sc1 += X.z * wk_v; sc2 += X.w * wk_v;
        }
    }
    const float inv = 0.25f;  // 1/sqrt(16)
    s2 *= inv; v20 *= inv; v21 *= inv; v22 *= inv;
    float ps = 0, pv0 = 0, pv1 = 0, pv2 = 0;
    if (act) {
        float a0 = wss[(sp * 3 + 0) * F + lane];
        float a1 = wss[(sp * 3 + 1) * F + lane];
        float a2 = wss[(sp * 3 + 2) * F + lane];
        float b0 = wsv[(sp * 2 + 0) * F + lane];
        float b1 = wsv[(sp * 2 + 1) * F + lane];
        ps = a0 * s2 + a1 * s2 * s2 + a2 * (v20 * v20 + v21 * v21 + v22 * v22);
        pv0 = b0 * v20 + b1 * s2 * v20;
        pv1 = b0 * v21 + b1 * s2 * v21;
        pv2 = b0 * v22 + b1 * s2 * v22;
    }
    __syncthreads();
    if (act) stA[wave][lane] = make_float4(ps, pv0, pv1, pv2);
    __syncthreads();
    if (!act) return;
    float fs = scs, f0 = sc0, f1 = sc1, f2 = sc2;
#pragma unroll 4
    for (int f = 0; f < F; ++f) {
        float4 P = stA[wave][f];
        float wl_s = WLs[f * F + lane], wl_v = WLv[f * F + lane];
        fs += P.x * wl_s; f0 += P.y * wl_v; f1 += P.z * wl_v; f2 += P.w * wl_v;
    }
    out_fs[(size_t)n * F + lane] = fs;
    float* fvp = out_fv + ((size_t)n * F + lane) * 3;
    fvp[0] = f0; fvp[1] = f1; fvp[2] = f2;
    float r = fs * Wout[lane];
#pragma unroll
    for (int off = 32; off > 0; off >>= 1) r += __shfl_down(r, off, 64);
    if (lane == 0) out0[n] = r;
}

extern "C" void kernel_launch(void* const* d_in, const int* in_sizes, int n_in,
                              void* d_out, int out_size, void* d_ws, size_t ws_size,
                              hipStream_t stream)
{
    const float* vectors = (const float*)d_in[0];
    const float* nfs  = (const float*)d_in[1];
    const float* nfv  = (const float*)d_in[2];
    const float* re   = (const float*)d_in[3];
    const float* Wus  = (const float*)d_in[4];
    const float* Wuv  = (const float*)d_in[5];
    const float* Wr1  = (const float*)d_in[6];
    const float* Wr2  = (const float*)d_in[7];
    const float* Wds  = (const float*)d_in[8];
    const float* Wdv  = (const float*)d_in[9];
    const float* wss  = (const float*)d_in[10];
    const float* wsv  = (const float*)d_in[11];
    const float* WLs  = (const float*)d_in[12];
    const float* WLv  = (const float*)d_in[13];
    const float* Wsks = (const float*)d_in[14];
    const float* Wskv = (const float*)d_in[15];
    const float* Wout = (const float*)d_in[16];
    const int* specie    = (const int*)d_in[17];
    const int* senders   = (const int*)d_in[18];
    const int* receivers = (const int*)d_in[19];

    const int N = in_sizes[1] / F;   // 50000
    const int E = in_sizes[18];      // 800000

    float* ws    = (float*)d_ws;
    float* s_lin = ws;                          // [N][F]
    float* v_lin = ws + (size_t)N * F;          // [N][3][F]
    float* agg_s = ws + (size_t)4 * N * F;      // [N][F]
    float* agg_v = ws + (size_t)5 * N * F;      // [N][3][F]

    hipMemsetAsync(agg_s, 0, (size_t)4 * N * F * sizeof(float), stream);

    const int nb = (N + 3) / 4;
    k_pre<<<nb, 256, 0, stream>>>(nfs, nfv, Wus, Wuv, s_lin, v_lin, N);
    k_edge<<<2048, 256, 0, stream>>>(vectors, re, Wr1, Wr2, senders, receivers,
                                     s_lin, v_lin, agg_s, agg_v, E);
    float* out0   = (float*)d_out;
    float* out_fs = out0 + N;
    float* out_fv = out_fs + (size_t)N * F;
    k_post<<<nb, 256, 0, stream>>>(agg_s, agg_v, nfs, nfv, Wds, Wdv, wss, wsv,
                                   WLs, WLv, Wsks, Wskv, Wout, specie,
                                   out0, out_fs, out_fv, N);
}

// Round 3
// 1219.849 us; speedup vs baseline: 1.1219x; 1.1219x over previous
//
#include <hip/hip_runtime.h>
#include <stdint.h>

#define F 64
#define RDIM 8
#define HDIM 64
#define NPATH 5

__device__ __forceinline__ unsigned short f2b(float f) {
    union { float f; unsigned int i; } v; v.f = f;
    unsigned int x = v.i;
    unsigned int r = x + 0x7fffu + ((x >> 16) & 1u);  // RNE
    return (unsigned short)(r >> 16);
}

// ---- Kernel A: comb[n][f][4] = (s@Wu_s, v@Wu_v per component) ------------------
__global__ __launch_bounds__(256) void k_pre(
    const float* __restrict__ nfs, const float* __restrict__ nfv,
    const float* __restrict__ Wus, const float* __restrict__ Wuv,
    float4* __restrict__ comb, int N)
{
    __shared__ float4 stage[4][F];
    const int wave = threadIdx.x >> 6, lane = threadIdx.x & 63;
    const int n = blockIdx.x * 4 + wave;
    const bool act = n < N;
    if (act) {
        float xs = nfs[(size_t)n * F + lane];
        const float* pv = nfv + ((size_t)n * F + lane) * 3;
        stage[wave][lane] = make_float4(xs, pv[0], pv[1], pv[2]);
    }
    __syncthreads();
    if (!act) return;
    float as = 0.f, a0 = 0.f, a1 = 0.f, a2 = 0.f;
#pragma unroll 8
    for (int f = 0; f < F; ++f) {
        float4 x = stage[wave][f];
        float ws = Wus[f * F + lane];
        float wv = Wuv[f * F + lane];
        as += x.x * ws; a0 += x.y * wv; a1 += x.z * wv; a2 += x.w * wv;
    }
    comb[(size_t)n * F + lane] = make_float4(as, a0, a1, a2);
}

// ---- Kernel B: radial MLP + tensor product + atomic scatter --------------------
__global__ __launch_bounds__(256, 4) void k_edge(
    const float* __restrict__ vecs, const float* __restrict__ re,
    const float* __restrict__ Wr1, const float* __restrict__ Wr2,
    const int* __restrict__ senders, const int* __restrict__ receivers,
    const float4* __restrict__ comb,
    float* __restrict__ agg_s, float* __restrict__ agg_v, int E)
{
    // W_r2 packed: dword d = k2*320 + (p*64+f) holds bf16(W[2k2][pf]) lo, bf16(W[2k2+1][pf]) hi
    __shared__ unsigned int w2p[(HDIM / 2) * NPATH * F];   // 40 KB
    const int tid = threadIdx.x;
    for (int d = tid; d < (HDIM / 2) * NPATH * F; d += 256) {
        int k2 = d / (NPATH * F), j = d - k2 * (NPATH * F);
        unsigned int lo = f2b(Wr2[(2 * k2) * (NPATH * F) + j]);
        unsigned int hi = f2b(Wr2[(2 * k2 + 1) * (NPATH * F) + j]);
        w2p[d] = lo | (hi << 16);
    }
    __syncthreads();

    const int wave = tid >> 6, lane = tid & 63;
    float w1r[RDIM];
#pragma unroll
    for (int r = 0; r < RDIM; ++r) w1r[r] = Wr1[r * HDIM + lane];

    const int gwave = blockIdx.x * 4 + wave;
    const int nwaves = gridDim.x * 4;
    const int nquad = (E + 7) >> 3;

    for (int q = gwave; q < nquad; q += nwaves) {
        const int ebase = q * 8;
        // --- phase 1: h[e, lane] for 8 edges (lane = hidden unit) ---
        float hh[8];
#pragma unroll
        for (int t = 0; t < 8; ++t) {
            const int e = ebase + t;
            float h = 0.f;
            if (e < E) {
                const float* rp = re + (size_t)e * RDIM;
#pragma unroll
                for (int r = 0; r < RDIM; ++r) h += rp[r] * w1r[r];
                h = h / (1.f + __expf(-h));        // silu
            }
            hh[t] = h;
        }

        // --- phase 2: acc[p][t] = sum_k h[t,k] * W_r2[k, p*F+lane] ---
        float acc[NPATH][8];
#pragma unroll
        for (int p = 0; p < NPATH; ++p)
#pragma unroll
            for (int t = 0; t < 8; ++t) acc[p][t] = 0.f;
#pragma unroll 8
        for (int k2 = 0; k2 < HDIM / 2; ++k2) {
            float hA[8], hB[8];
#pragma unroll
            for (int t = 0; t < 8; ++t) {
                hA[t] = __shfl(hh[t], 2 * k2, 64);
                hB[t] = __shfl(hh[t], 2 * k2 + 1, 64);
            }
#pragma unroll
            for (int p = 0; p < NPATH; ++p) {
                unsigned int wp = w2p[k2 * (NPATH * F) + p * F + lane];
                union { unsigned int i; float f; } lo, hi;
                lo.i = wp << 16; hi.i = wp & 0xffff0000u;
#pragma unroll
                for (int t = 0; t < 8; ++t)
                    acc[p][t] += lo.f * hA[t] + hi.f * hB[t];
            }
        }

        // --- phase 3: tensor product + atomic scatter ---
        if (ebase + 8 <= E) {
            const int4 sA = *(const int4*)(senders + ebase);
            const int4 sB = *(const int4*)(senders + ebase + 4);
            const int4 rA = *(const int4*)(receivers + ebase);
            const int4 rB = *(const int4*)(receivers + ebase + 4);
            const int sd[8] = {sA.x, sA.y, sA.z, sA.w, sB.x, sB.y, sB.z, sB.w};
            const int rc[8] = {rA.x, rA.y, rA.z, rA.w, rB.x, rB.y, rB.z, rB.w};
            float vv[24];
            const float4* v4 = (const float4*)(vecs + (size_t)ebase * 3);
#pragma unroll
            for (int j = 0; j < 6; ++j) ((float4*)vv)[j] = v4[j];

            float4 g = comb[(size_t)sd[0] * F + lane];
#pragma unroll
            for (int t = 0; t < 8; ++t) {
                float4 gn;
                if (t < 7) gn = comb[(size_t)sd[t + 1] * F + lane];
                float vx = vv[3 * t], vy = vv[3 * t + 1], vz = vv[3 * t + 2];
                float nrm = sqrtf(vx * vx + vy * vy + vz * vz);
                float inv = 1.f / (nrm + 1e-9f);
                float Yx = vx * inv, Yy = vy * inv, Yz = vz * inv;
                float xs = g.x, x0 = g.y, x1 = g.z, x2 = g.w;
                float w0 = acc[0][t], w1p = acc[1][t], w2p_ = acc[2][t],
                      w3p = acc[3][t], w4p = acc[4][t];
                float dvY = x0 * Yx + x1 * Yy + x2 * Yz;
                float ms = w0 * xs + w3p * dvY;
                float m0 = w1p * xs * Yx + w2p_ * x0 + w4p * (x1 * Yz - x2 * Yy);
                float m1 = w1p * xs * Yy + w2p_ * x1 + w4p * (x2 * Yx - x0 * Yz);
                float m2 = w1p * xs * Yz + w2p_ * x2 + w4p * (x0 * Yy - x1 * Yx);
                const int rcv = rc[t];
                float* asb = agg_s + (size_t)rcv * F;
                float* avb = agg_v + (size_t)rcv * 3 * F;
                unsafeAtomicAdd(&asb[lane], ms);
                unsafeAtomicAdd(&avb[lane], m0);
                unsafeAtomicAdd(&avb[F + lane], m1);
                unsafeAtomicAdd(&avb[2 * F + lane], m2);
                g = gn;
            }
        } else {
            for (int t = 0; t < 8; ++t) {
                const int e = ebase + t;
                if (e >= E) continue;
                const int snd = senders[e], rcv = receivers[e];
                const float* vp = vecs + (size_t)e * 3;
                float vx = vp[0], vy = vp[1], vz = vp[2];
                float nrm = sqrtf(vx * vx + vy * vy + vz * vz);
                float inv = 1.f / (nrm + 1e-9f);
                float Yx = vx * inv, Yy = vy * inv, Yz = vz * inv;
                float4 g = comb[(size_t)snd * F + lane];
                float xs = g.x, x0 = g.y, x1 = g.z, x2 = g.w;
                float w0 = acc[0][t], w1p = acc[1][t], w2p_ = acc[2][t],
                      w3p = acc[3][t], w4p = acc[4][t];
                float dvY = x0 * Yx + x1 * Yy + x2 * Yz;
                float ms = w0 * xs + w3p * dvY;
                float m0 = w1p * xs * Yx + w2p_ * x0 + w4p * (x1 * Yz - x2 * Yy);
                float m1 = w1p * xs * Yy + w2p_ * x1 + w4p * (x2 * Yx - x0 * Yz);
                float m2 = w1p * xs * Yz + w2p_ * x2 + w4p * (x0 * Yy - x1 * Yx);
                float* asb = agg_s + (size_t)rcv * F;
                float* avb = agg_v + (size_t)rcv * 3 * F;
                unsafeAtomicAdd(&asb[lane], ms);
                unsafeAtomicAdd(&avb[lane], m0);
                unsafeAtomicAdd(&avb[F + lane], m1);
                unsafeAtomicAdd(&avb[2 * F + lane], m2);
            }
        }
    }
}

// ---- Kernel C: linear-down, sym contraction, skip, readout ---------------------
__global__ __launch_bounds__(256) void k_post(
    const float* __restrict__ agg_s, const float* __restrict__ agg_v,
    const float* __restrict__ nfs, const float* __restrict__ nfv,
    const float* __restrict__ Wds, const float* __restrict__ Wdv,
    const float* __restrict__ wss, const float* __restrict__ wsv,
    const float* __restrict__ WLs, const float* __restrict__ WLv,
    const float* __restrict__ Wsks, const float* __restrict__ Wskv,
    const float* __restrict__ Wout, const int* __restrict__ specie,
    float* __restrict__ out0, float* __restrict__ out_fs,
    float* __restrict__ out_fv, int N)
{
    __shared__ float4 stA[4][F];
    __shared__ float4 stX[4][F];
    const int wave = threadIdx.x >> 6, lane = threadIdx.x & 63;
    const int n = blockIdx.x * 4 + wave;
    const bool act = n < N;
    const int sp = act ? specie[n] : 0;
    if (act) {
        float as = agg_s[(size_t)n * F + lane];
        const float* avb = agg_v + (size_t)n * 3 * F;
        stA[wave][lane] = make_float4(as, avb[lane], avb[F + lane], avb[2 * F + lane]);
        float xs = nfs[(size_t)n * F + lane];
        const float* xp = nfv + ((size_t)n * F + lane) * 3;
        stX[wave][lane] = make_float4(xs, xp[0], xp[1], xp[2]);
    }
    __syncthreads();

    float s2 = 0, v20 = 0, v21 = 0, v22 = 0, scs = 0, sc0 = 0, sc1 = 0, sc2 = 0;
    const float* Wks = Wsks + (size_t)sp * F * F;
    const float* Wkv = Wskv + (size_t)sp * F * F;
    if (act) {
#pragma unroll 4
        for (int f = 0; f < F; ++f) {
            float4 A = stA[wave][f];
            float4 X = stX[wave][f];
            float wd_s = Wds[f * F + lane], wd_v = Wdv[f * F + lane];
            s2 += A.x * wd_s; v20 += A.y * wd_v; v21 += A.z * wd_v; v22 += A.w * wd_v;
            float wk_s = Wks[f * F + lane], wk_v = Wkv[f * F + lane];
            scs += X.x * wk_s; sc0 += X.y * wk_v; sc1 += X.z * wk_v; sc2 += X.w * wk_v;
        }
    }
    const float inv = 0.25f;  // 1/sqrt(16)
    s2 *= inv; v20 *= inv; v21 *= inv; v22 *= inv;
    float ps = 0, pv0 = 0, pv1 = 0, pv2 = 0;
    if (act) {
        float a0 = wss[(sp * 3 + 0) * F + lane];
        float a1 = wss[(sp * 3 + 1) * F + lane];
        float a2 = wss[(sp * 3 + 2) * F + lane];
        float b0 = wsv[(sp * 2 + 0) * F + lane];
        float b1 = wsv[(sp * 2 + 1) * F + lane];
        ps = a0 * s2 + a1 * s2 * s2 + a2 * (v20 * v20 + v21 * v21 + v22 * v22);
        pv0 = b0 * v20 + b1 * s2 * v20;
        pv1 = b0 * v21 + b1 * s2 * v21;
        pv2 = b0 * v22 + b1 * s2 * v22;
    }
    __syncthreads();
    if (act) stA[wave][lane] = make_float4(ps, pv0, pv1, pv2);
    __syncthreads();
    if (!act) return;
    float fs = scs, f0 = sc0, f1 = sc1, f2 = sc2;
#pragma unroll 4
    for (int f = 0; f < F; ++f) {
        float4 P = stA[wave][f];
        float wl_s = WLs[f * F + lane], wl_v = WLv[f * F + lane];
        fs += P.x * wl_s; f0 += P.y * wl_v; f1 += P.z * wl_v; f2 += P.w * wl_v;
    }
    out_fs[(size_t)n * F + lane] = fs;
    float* fvp = out_fv + ((size_t)n * F + lane) * 3;
    fvp[0] = f0; fvp[1] = f1; fvp[2] = f2;
    float r = fs * Wout[lane];
#pragma unroll
    for (int off = 32; off > 0; off >>= 1) r += __shfl_down(r, off, 64);
    if (lane == 0) out0[n] = r;
}

extern "C" void kernel_launch(void* const* d_in, const int* in_sizes, int n_in,
                              void* d_out, int out_size, void* d_ws, size_t ws_size,
                              hipStream_t stream)
{
    const float* vectors = (const float*)d_in[0];
    const float* nfs  = (const float*)d_in[1];
    const float* nfv  = (const float*)d_in[2];
    const float* re   = (const float*)d_in[3];
    const float* Wus  = (const float*)d_in[4];
    const float* Wuv  = (const float*)d_in[5];
    const float* Wr1  = (const float*)d_in[6];
    const float* Wr2  = (const float*)d_in[7];
    const float* Wds  = (const float*)d_in[8];
    const float* Wdv  = (const float*)d_in[9];
    const float* wss  = (const float*)d_in[10];
    const float* wsv  = (const float*)d_in[11];
    const float* WLs  = (const float*)d_in[12];
    const float* WLv  = (const float*)d_in[13];
    const float* Wsks = (const float*)d_in[14];
    const float* Wskv = (const float*)d_in[15];
    const float* Wout = (const float*)d_in[16];
    const int* specie    = (const int*)d_in[17];
    const int* senders   = (const int*)d_in[18];
    const int* receivers = (const int*)d_in[19];

    const int N = in_sizes[1] / F;   // 50000
    const int E = in_sizes[18];      // 800000

    float* ws    = (float*)d_ws;
    float4* comb = (float4*)ws;                 // [N][F] float4 = 4NF floats
    float* agg_s = ws + (size_t)4 * N * F;      // [N][F]
    float* agg_v = ws + (size_t)5 * N * F;      // [N][3][F]

    hipMemsetAsync(agg_s, 0, (size_t)4 * N * F * sizeof(float), stream);

    const int nb = (N + 3) / 4;
    k_pre<<<nb, 256, 0, stream>>>(nfs, nfv, Wus, Wuv, comb, N);
    k_edge<<<2048, 256, 0, stream>>>(vectors, re, Wr1, Wr2, senders, receivers,
                                     comb, agg_s, agg_v, E);
    float* out0   = (float*)d_out;
    float* out_fs = out0 + N;
    float* out_fv = out_fs + (size_t)N * F;
    k_post<<<nb, 256, 0, stream>>>(agg_s, agg_v, nfs, nfv, Wds, Wdv, wss, wsv,
                                   WLs, WLv, Wsks, Wskv, Wout, specie,
                                   out0, out_fs, out_fv, N);
}

// Round 4
// 1043.825 us; speedup vs baseline: 1.3111x; 1.1686x over previous
//
#include <hip/hip_runtime.h>
#include <stdint.h>

#define F 64
#define RDIM 8
#define HDIM 64
#define NPATH 5
#define EB 64            // edges per block-iteration
#define PADH 72          // h_lds row stride (f16 elems), 144B: 16B-aligned rows
#define PADN 324         // w_lds row stride (f16 elems)

typedef _Float16 half8 __attribute__((ext_vector_type(8)));
typedef float floatx4 __attribute__((ext_vector_type(4)));

// ---- Kernel A: comb[n][f] = (s@Wu_s, v@Wu_v per component) as float4 -----------
__global__ __launch_bounds__(256) void k_pre(
    const float* __restrict__ nfs, const float* __restrict__ nfv,
    const float* __restrict__ Wus, const float* __restrict__ Wuv,
    float4* __restrict__ comb, int N)
{
    __shared__ float4 stage[4][F];
    const int wave = threadIdx.x >> 6, lane = threadIdx.x & 63;
    const int n = blockIdx.x * 4 + wave;
    const bool act = n < N;
    if (act) {
        float xs = nfs[(size_t)n * F + lane];
        const float* pv = nfv + ((size_t)n * F + lane) * 3;
        stage[wave][lane] = make_float4(xs, pv[0], pv[1], pv[2]);
    }
    __syncthreads();
    if (!act) return;
    float as = 0.f, a0 = 0.f, a1 = 0.f, a2 = 0.f;
#pragma unroll 8
    for (int f = 0; f < F; ++f) {
        float4 x = stage[wave][f];
        float ws = Wus[f * F + lane];
        float wv = Wuv[f * F + lane];
        as += x.x * ws; a0 += x.y * wv; a1 += x.z * wv; a2 += x.w * wv;
    }
    comb[(size_t)n * F + lane] = make_float4(as, a0, a1, a2);
}

// ---- Kernel B: radial MLP (MFMA) + tensor product + atomic scatter -------------
__global__ __launch_bounds__(256, 3) void k_edge(
    const float* __restrict__ vecs, const float* __restrict__ re,
    const float* __restrict__ Wr1, const float* __restrict__ Wr2,
    const int* __restrict__ senders, const int* __restrict__ receivers,
    const float4* __restrict__ comb,
    float* __restrict__ agg_s, float* __restrict__ agg_v, int E)
{
    __shared__ _Float16 h_lds[EB * PADH];   // ~9 KB
    __shared__ _Float16 w_lds[EB * PADN];   // ~40.5 KB
    const int tid = threadIdx.x;
    const int wave = tid >> 6, lane = tid & 63;
    const int l15 = lane & 15, lq = lane >> 4;

    // Persistent B-fragments: this wave's 80-col slice of W_r2 (f16).
    // B layout (16x16x32): lane holds B[k = ks*32 + lq*8 + j][n = l15].
    half8 bfrag[5][2];
#pragma unroll
    for (int nt = 0; nt < 5; ++nt)
#pragma unroll
        for (int ks = 0; ks < 2; ++ks)
#pragma unroll
            for (int j = 0; j < 8; ++j) {
                int k = ks * 32 + lq * 8 + j;
                int n = wave * 80 + nt * 16 + l15;
                bfrag[nt][ks][j] = (_Float16)Wr2[k * (NPATH * F) + n];
            }

    float w1r[RDIM];
#pragma unroll
    for (int r = 0; r < RDIM; ++r) w1r[r] = Wr1[r * HDIM + lane];

    const int niter = (E + EB - 1) / EB;
    for (int it = blockIdx.x; it < niter; it += gridDim.x) {
        const int base = it * EB;

        // --- phase 1: h for this wave's 16 edges (lane = hidden unit) ---
#pragma unroll 4
        for (int t = 0; t < 16; ++t) {
            const int eloc = wave * 16 + t;
            const int e = base + eloc;
            float h = 0.f;
            if (e < E) {
                const float4* rp = (const float4*)(re + (size_t)e * RDIM);
                float4 ra = rp[0], rb = rp[1];
                h = ra.x * w1r[0] + ra.y * w1r[1] + ra.z * w1r[2] + ra.w * w1r[3]
                  + rb.x * w1r[4] + rb.y * w1r[5] + rb.z * w1r[6] + rb.w * w1r[7];
                h = h / (1.f + __expf(-h));   // silu
            }
            h_lds[eloc * PADH + lane] = (_Float16)h;
        }
        __syncthreads();

        // --- phase 2: W(64 x 320) = H(64 x 64) @ Wr2(64 x 320) via MFMA ---
        floatx4 c[4][5];
#pragma unroll
        for (int mt = 0; mt < 4; ++mt)
#pragma unroll
            for (int nt = 0; nt < 5; ++nt)
                c[mt][nt] = (floatx4){0.f, 0.f, 0.f, 0.f};
#pragma unroll
        for (int ks = 0; ks < 2; ++ks) {
            half8 a[4];
#pragma unroll
            for (int mt = 0; mt < 4; ++mt)  // A: lane holds A[m=l15][k=ks*32+lq*8+j]
                a[mt] = *(const half8*)&h_lds[(mt * 16 + l15) * PADH + ks * 32 + lq * 8];
#pragma unroll
            for (int mt = 0; mt < 4; ++mt)
#pragma unroll
                for (int nt = 0; nt < 5; ++nt)
                    c[mt][nt] = __builtin_amdgcn_mfma_f32_16x16x32_f16(
                        a[mt], bfrag[nt][ks], c[mt][nt], 0, 0, 0);
        }
        // C/D layout: col = l15, row = lq*4 + r
#pragma unroll
        for (int mt = 0; mt < 4; ++mt)
#pragma unroll
            for (int nt = 0; nt < 5; ++nt)
#pragma unroll
                for (int r = 0; r < 4; ++r) {
                    int row = mt * 16 + lq * 4 + r;
                    int col = wave * 80 + nt * 16 + l15;
                    w_lds[row * PADN + col] = (_Float16)c[mt][nt][r];
                }
        __syncthreads();

        // --- phase 3: tensor product + atomic scatter (16 edges / wave) ---
        if (base + EB <= E) {
            const int ew = base + wave * 16;
            int sd[16], rc[16];
#pragma unroll
            for (int j = 0; j < 4; ++j) {
                ((int4*)sd)[j] = ((const int4*)(senders + ew))[j];
                ((int4*)rc)[j] = ((const int4*)(receivers + ew))[j];
            }
            float4 g = comb[(size_t)sd[0] * F + lane];
#pragma unroll
            for (int t = 0; t < 16; ++t) {
                float4 gn;
                if (t < 15) gn = comb[(size_t)sd[t + 1] * F + lane];
                const int eloc = wave * 16 + t;
                const float* vp = vecs + (size_t)(ew + t) * 3;
                float vx = vp[0], vy = vp[1], vz = vp[2];
                float nrm = sqrtf(vx * vx + vy * vy + vz * vz);
                float inv = 1.f / (nrm + 1e-9f);
                float Yx = vx * inv, Yy = vy * inv, Yz = vz * inv;
                float w0  = (float)w_lds[eloc * PADN + 0 * F + lane];
                float w1p = (float)w_lds[eloc * PADN + 1 * F + lane];
                float w2p = (float)w_lds[eloc * PADN + 2 * F + lane];
                float w3p = (float)w_lds[eloc * PADN + 3 * F + lane];
                float w4p = (float)w_lds[eloc * PADN + 4 * F + lane];
                float xs = g.x, x0 = g.y, x1 = g.z, x2 = g.w;
                float dvY = x0 * Yx + x1 * Yy + x2 * Yz;
                float ms = w0 * xs + w3p * dvY;
                float m0 = w1p * xs * Yx + w2p * x0 + w4p * (x1 * Yz - x2 * Yy);
                float m1 = w1p * xs * Yy + w2p * x1 + w4p * (x2 * Yx - x0 * Yz);
                float m2 = w1p * xs * Yz + w2p * x2 + w4p * (x0 * Yy - x1 * Yx);
                const int rcv = rc[t];
                float* asb = agg_s + (size_t)rcv * F;
                float* avb = agg_v + (size_t)rcv * 3 * F;
                unsafeAtomicAdd(&asb[lane], ms);
                unsafeAtomicAdd(&avb[lane], m0);
                unsafeAtomicAdd(&avb[F + lane], m1);
                unsafeAtomicAdd(&avb[2 * F + lane], m2);
                g = gn;
            }
        } else {
            for (int t = 0; t < 16; ++t) {
                const int eloc = wave * 16 + t;
                const int e = base + eloc;
                if (e >= E) break;
                const int snd = senders[e], rcv = receivers[e];
                const float* vp = vecs + (size_t)e * 3;
                float vx = vp[0], vy = vp[1], vz = vp[2];
                float nrm = sqrtf(vx * vx + vy * vy + vz * vz);
                float inv = 1.f / (nrm + 1e-9f);
                float Yx = vx * inv, Yy = vy * inv, Yz = vz * inv;
                float4 g = comb[(size_t)snd * F + lane];
                float w0  = (float)w_lds[eloc * PADN + 0 * F + lane];
                float w1p = (float)w_lds[eloc * PADN + 1 * F + lane];
                float w2p = (float)w_lds[eloc * PADN + 2 * F + lane];
                float w3p = (float)w_lds[eloc * PADN + 3 * F + lane];
                float w4p = (float)w_lds[eloc * PADN + 4 * F + lane];
                float xs = g.x, x0 = g.y, x1 = g.z, x2 = g.w;
                float dvY = x0 * Yx + x1 * Yy + x2 * Yz;
                float ms = w0 * xs + w3p * dvY;
                float m0 = w1p * xs * Yx + w2p * x0 + w4p * (x1 * Yz - x2 * Yy);
                float m1 = w1p * xs * Yy + w2p * x1 + w4p * (x2 * Yx - x0 * Yz);
                float m2 = w1p * xs * Yz + w2p * x2 + w4p * (x0 * Yy - x1 * Yx);
                float* asb = agg_s + (size_t)rcv * F;
                float* avb = agg_v + (size_t)rcv * 3 * F;
                unsafeAtomicAdd(&asb[lane], ms);
                unsafeAtomicAdd(&avb[lane], m0);
                unsafeAtomicAdd(&avb[F + lane], m1);
                unsafeAtomicAdd(&avb[2 * F + lane], m2);
            }
        }
    }
}

// ---- Kernel C: linear-down, sym contraction, skip, readout ---------------------
__global__ __launch_bounds__(256) void k_post(
    const float* __restrict__ agg_s, const float* __restrict__ agg_v,
    const float* __restrict__ nfs, const float* __restrict__ nfv,
    const float* __restrict__ Wds, const float* __restrict__ Wdv,
    const float* __restrict__ wss, const float* __restrict__ wsv,
    const float* __restrict__ WLs, const float* __restrict__ WLv,
    const float* __restrict__ Wsks, const float* __restrict__ Wskv,
    const float* __restrict__ Wout, const int* __restrict__ specie,
    float* __restrict__ out0, float* __restrict__ out_fs,
    float* __restrict__ out_fv, int N)
{
    __shared__ float4 stA[4][F];
    __shared__ float4 stX[4][F];
    const int wave = threadIdx.x >> 6, lane = threadIdx.x & 63;
    const int n = blockIdx.x * 4 + wave;
    const bool act = n < N;
    const int sp = act ? specie[n] : 0;
    if (act) {
        float as = agg_s[(size_t)n * F + lane];
        const float* avb = agg_v + (size_t)n * 3 * F;
        stA[wave][lane] = make_float4(as, avb[lane], avb[F + lane], avb[2 * F + lane]);
        float xs = nfs[(size_t)n * F + lane];
        const float* xp = nfv + ((size_t)n * F + lane) * 3;
        stX[wave][lane] = make_float4(xs, xp[0], xp[1], xp[2]);
    }
    __syncthreads();

    float s2 = 0, v20 = 0, v21 = 0, v22 = 0, scs = 0, sc0 = 0, sc1 = 0, sc2 = 0;
    const float* Wks = Wsks + (size_t)sp * F * F;
    const float* Wkv = Wskv + (size_t)sp * F * F;
    if (act) {
#pragma unroll 4
        for (int f = 0; f < F; ++f) {
            float4 A = stA[wave][f];
            float4 X = stX[wave][f];
            float wd_s = Wds[f * F + lane], wd_v = Wdv[f * F + lane];
            s2 += A.x * wd_s; v20 += A.y * wd_v; v21 += A.z * wd_v; v22 += A.w * wd_v;
            float wk_s = Wks[f * F + lane], wk_v = Wkv[f * F + lane];
            scs += X.x * wk_s; sc0 += X.y * wk_v; sc1 += X.z * wk_v; sc2 += X.w * wk_v;
        }
    }
    const float inv = 0.25f;  // 1/sqrt(16)
    s2 *= inv; v20 *= inv; v21 *= inv; v22 *= inv;
    float ps = 0, pv0 = 0, pv1 = 0, pv2 = 0;
    if (act) {
        float a0 = wss[(sp * 3 + 0) * F + lane];
        float a1 = wss[(sp * 3 + 1) * F + lane];
        float a2 = wss[(sp * 3 + 2) * F + lane];
        float b0 = wsv[(sp * 2 + 0) * F + lane];
        float b1 = wsv[(sp * 2 + 1) * F + lane];
        ps = a0 * s2 + a1 * s2 * s2 + a2 * (v20 * v20 + v21 * v21 + v22 * v22);
        pv0 = b0 * v20 + b1 * s2 * v20;
        pv1 = b0 * v21 + b1 * s2 * v21;
        pv2 = b0 * v22 + b1 * s2 * v22;
    }
    __syncthreads();
    if (act) stA[wave][lane] = make_float4(ps, pv0, pv1, pv2);
    __syncthreads();
    if (!act) return;
    float fs = scs, f0 = sc0, f1 = sc1, f2 = sc2;
#pragma unroll 4
    for (int f = 0; f < F; ++f) {
        float4 P = stA[wave][f];
        float wl_s = WLs[f * F + lane], wl_v = WLv[f * F + lane];
        fs += P.x * wl_s; f0 += P.y * wl_v; f1 += P.z * wl_v; f2 += P.w * wl_v;
    }
    out_fs[(size_t)n * F + lane] = fs;
    float* fvp = out_fv + ((size_t)n * F + lane) * 3;
    fvp[0] = f0; fvp[1] = f1; fvp[2] = f2;
    float r = fs * Wout[lane];
#pragma unroll
    for (int off = 32; off > 0; off >>= 1) r += __shfl_down(r, off, 64);
    if (lane == 0) out0[n] = r;
}

extern "C" void kernel_launch(void* const* d_in, const int* in_sizes, int n_in,
                              void* d_out, int out_size, void* d_ws, size_t ws_size,
                              hipStream_t stream)
{
    const float* vectors = (const float*)d_in[0];
    const float* nfs  = (const float*)d_in[1];
    const float* nfv  = (const float*)d_in[2];
    const float* re   = (const float*)d_in[3];
    const float* Wus  = (const float*)d_in[4];
    const float* Wuv  = (const float*)d_in[5];
    const float* Wr1  = (const float*)d_in[6];
    const float* Wr2  = (const float*)d_in[7];
    const float* Wds  = (const float*)d_in[8];
    const float* Wdv  = (const float*)d_in[9];
    const float* wss  = (const float*)d_in[10];
    const float* wsv  = (const float*)d_in[11];
    const float* WLs  = (const float*)d_in[12];
    const float* WLv  = (const float*)d_in[13];
    const float* Wsks = (const float*)d_in[14];
    const float* Wskv = (const float*)d_in[15];
    const float* Wout = (const float*)d_in[16];
    const int* specie    = (const int*)d_in[17];
    const int* senders   = (const int*)d_in[18];
    const int* receivers = (const int*)d_in[19];

    const int N = in_sizes[1] / F;   // 50000
    const int E = in_sizes[18];      // 800000

    float* ws    = (float*)d_ws;
    float4* comb = (float4*)ws;                 // [N][F] float4
    float* agg_s = ws + (size_t)4 * N * F;      // [N][F]
    float* agg_v = ws + (size_t)5 * N * F;      // [N][3][F]

    hipMemsetAsync(agg_s, 0, (size_t)4 * N * F * sizeof(float), stream);

    const int nb = (N + 3) / 4;
    k_pre<<<nb, 256, 0, stream>>>(nfs, nfv, Wus, Wuv, comb, N);
    k_edge<<<2048, 256, 0, stream>>>(vectors, re, Wr1, Wr2, senders, receivers,
                                     comb, agg_s, agg_v, E);
    float* out0   = (float*)d_out;
    float* out_fs = out0 + N;
    float* out_fv = out_fs + (size_t)N * F;
    k_post<<<nb, 256, 0, stream>>>(agg_s, agg_v, nfs, nfv, Wds, Wdv, wss, wsv,
                                   WLs, WLv, Wsks, Wskv, Wout, specie,
                                   out0, out_fs, out_fv, N);
}